// Round 1
// 560.283 us; speedup vs baseline: 1.2163x; 1.2163x over previous
//
#include <hip/hip_runtime.h>
#include <hip/hip_bf16.h>
#include <float.h>

#define DECAY 0.99f
#define OMD   0.01f
#define EPSF  1e-6f

constexpr int Bb = 8, Ss = 8192, Dd = 256, Kk = 2048;
constexpr int Nn = Bb * Ss;                 // 65536 rows

// ---- output layout (floats) ----
constexpr long OUT_QUANT = 0;                         // 16777216 floats
constexpr long OUT_IND   = (long)Nn * Dd;             // 16777216
constexpr long OUT_NCS   = OUT_IND + Nn;              // 16842752
constexpr long OUT_NEA   = OUT_NCS + Kk;              // 16844800
constexpr long OUT_NE    = OUT_NEA + (long)Kk * Dd;   // 17369088

// ---- workspace layout (floats) ----
constexpr long WS_COUNTS = 0;                         // K
constexpr long WS_TOTAL  = 2048;                      // 1
constexpr long WS_EE     = 2112;                      // K
constexpr long WS_BIG    = 4160;                      // embed_sum (atomic path)
                                                      // or 8 partials (ws path)
constexpr int  PARTS     = 8;                         // strip split for segsum

typedef __attribute__((ext_vector_type(8))) short short8;
typedef __attribute__((ext_vector_type(4))) float floatx4;

// split-bf16 certainty window: rows whose approx top-2 gap <= WINDOW get an
// exact fp32 rescan in pass 2.
#define WINDOW 0.0625f

// async global->LDS, 16B per lane, LDS dest = wave-uniform base + lane*16
__device__ __forceinline__ void gl_lds(const ushort* g, ushort* l)
{
    __builtin_amdgcn_global_load_lds(
        (const __attribute__((address_space(1))) void*)g,
        (__attribute__((address_space(3))) void*)l,
        16, 0, 0);
}

// ============================================================
// Kernel A: x -> x_hi(bf16), x_lo = bf16(x - x_hi)
// ============================================================
__global__ __launch_bounds__(256) void convert_x_kernel(
    const float* __restrict__ x, ushort* __restrict__ x_hi, ushort* __restrict__ x_lo)
{
    long base = ((long)blockIdx.x * 256 + threadIdx.x) * 4;
    float4 v = *(const float4*)&x[base];
    float vv[4] = {v.x, v.y, v.z, v.w};
    ushort hh[4], ll[4];
    #pragma unroll
    for (int i = 0; i < 4; ++i) {
        __hip_bfloat16 hb = __float2bfloat16(vv[i]);
        float r = vv[i] - __bfloat162float(hb);
        __hip_bfloat16 lb = __float2bfloat16(r);
        hh[i] = *(ushort*)&hb; ll[i] = *(ushort*)&lb;
    }
    ushort4 h; h.x = hh[0]; h.y = hh[1]; h.z = hh[2]; h.w = hh[3];
    ushort4 l; l.x = ll[0]; l.y = ll[1]; l.z = ll[2]; l.w = ll[3];
    *(ushort4*)&x_hi[base] = h;
    *(ushort4*)&x_lo[base] = l;
}

// ============================================================
// Kernel B: embed -> e_hi, e_lo and ee[k] = sum_d embed[k][d]^2
// ============================================================
__global__ __launch_bounds__(256) void convert_e_kernel(
    const float* __restrict__ embed, ushort* __restrict__ e_hi,
    ushort* __restrict__ e_lo, float* __restrict__ ee)
{
    int row  = blockIdx.x * 4 + (threadIdx.x >> 6);
    int lane = threadIdx.x & 63;
    long base = (long)row * Dd + lane * 4;
    float4 v = *(const float4*)&embed[base];
    float vv[4] = {v.x, v.y, v.z, v.w};
    ushort hh[4], ll[4];
    float s = 0.0f;
    #pragma unroll
    for (int i = 0; i < 4; ++i) {
        s += vv[i] * vv[i];
        __hip_bfloat16 hb = __float2bfloat16(vv[i]);
        float r = vv[i] - __bfloat162float(hb);
        __hip_bfloat16 lb = __float2bfloat16(r);
        hh[i] = *(ushort*)&hb; ll[i] = *(ushort*)&lb;
    }
    ushort4 h; h.x = hh[0]; h.y = hh[1]; h.z = hh[2]; h.w = hh[3];
    ushort4 l; l.x = ll[0]; l.y = ll[1]; l.z = ll[2]; l.w = ll[3];
    *(ushort4*)&e_hi[base] = h;
    *(ushort4*)&e_lo[base] = l;
    #pragma unroll
    for (int off = 32; off >= 1; off >>= 1)
        s += __shfl_xor(s, off, 64);
    if (lane == 0) ee[row] = s;
}

// ============================================================
// Kernel C (pass 1): MFMA split-bf16 fused GEMM + top-2 argmin.
//
// v2 restructure (this round):
//  * merged k-loop: per 32-wide k chunk stage {a_hi,a_lo,b_hi,b_lo} ONCE and
//    run all 3 combos (hi*hi, lo*hi, hi*lo) -> 33% less LDS+global traffic,
//    3x fewer barriers (8 staging rounds/ct instead of 24).
//  * global_load_lds width=16 staging (no VGPR round-trip, no ds_write).
//  * conflict-free swizzle: row pitch 64B, 16B chunk c stored at slot
//    c ^ ((row>>1)&3). gl_lds writes linearly, so the global SOURCE address
//    is pre-swizzled (same involution); the ds_read_b128 fragment reads
//    apply the swizzle on the read address. Each wave frag read is then a
//    permutation of a contiguous 1KB region -> 2-way max (free).
// ============================================================
__global__ __attribute__((amdgpu_waves_per_eu(2, 2))) __launch_bounds__(256)
void pass1_kernel(
    const ushort* __restrict__ x_hi, const ushort* __restrict__ x_lo,
    const ushort* __restrict__ e_hi, const ushort* __restrict__ e_lo,
    const float* __restrict__ ee, float* __restrict__ ind_out,
    int* __restrict__ qbase)
{
    // 4 tiles of [128 rows][32 bf16] = 8KB each
    __shared__ __attribute__((aligned(16))) ushort ah[128 * 32];
    __shared__ __attribute__((aligned(16))) ushort al[128 * 32];
    __shared__ __attribute__((aligned(16))) ushort bh[128 * 32];
    __shared__ __attribute__((aligned(16))) ushort bl[128 * 32];
    __shared__ float  redv[2][128];
    __shared__ float  red2[2][128];
    __shared__ int    redi[2][128];

    const int tid  = threadIdx.x;
    const int lane = tid & 63;
    const int quad = lane >> 4;
    const int l15  = lane & 15;
    const int w    = tid >> 6;
    const int wy   = w >> 1;
    const int wx   = w & 1;
    const long row0 = (long)blockIdx.x * 128;

    // ---- staging source pre-swizzle (per-lane, seg-invariant) ----
    // lane covers (rloc = lane>>2, slot_lin = lane&3) of a 16-row segment;
    // chunk written to slot_lin must be slot_lin ^ ((row>>1)&3); seg*16
    // doesn't affect (row>>1)&3, so it reduces to rloc.
    const int rloc   = lane >> 2;
    const int cchunk = (lane & 3) ^ ((rloc >> 1) & 3);
    const int gcoff  = rloc * 256 + cchunk * 8;   // ushort offset from (seg row0, kcol)

    // ---- fragment read swizzle ----
    const int sread = (l15 >> 1) & 3;
    const int aoff0 = ((wy * 64 + l15) << 5) + ((quad ^ sread) << 3);
    const int boff0 = ((wx * 64 + l15) << 5) + ((quad ^ sread) << 3);

    float bestv[16], best2v[16];
    int   besti[16];
    #pragma unroll
    for (int i = 0; i < 16; ++i) { bestv[i] = FLT_MAX; best2v[i] = FLT_MAX; besti[i] = 0; }

    // each wave stages segments {w, w+4} (16 rows = 1KB each) of each buffer
#define STAGE(buf, srcp, rowbase)                                              \
    {                                                                          \
        gl_lds(&srcp[(((long)(rowbase) + (w) * 16) << 8) + kcol + gcoff],      \
               &buf[(w) * 512]);                                               \
        gl_lds(&srcp[(((long)(rowbase) + (w + 4) * 16) << 8) + kcol + gcoff],  \
               &buf[(w + 4) * 512]);                                           \
    }

    for (int ct = 0; ct < Kk / 128; ++ct) {
        floatx4 acc[4][4];
        #pragma unroll
        for (int rt = 0; rt < 4; ++rt)
            #pragma unroll
            for (int jt = 0; jt < 4; ++jt)
                acc[rt][jt] = (floatx4){0.f, 0.f, 0.f, 0.f};

        const long brow = (long)ct * 128;

        for (int kc = 0; kc < 8; ++kc) {
            const int kcol = kc * 32;

            __syncthreads();                 // prior round's frag reads done
            STAGE(ah, x_hi, row0);
            STAGE(al, x_lo, row0);
            STAGE(bh, e_hi, brow);
            STAGE(bl, e_lo, brow);
            __syncthreads();                 // vmcnt(0) drain + barrier

            short8 afh[4], bfh[4], afl[4], bfl[4];
            #pragma unroll
            for (int rt = 0; rt < 4; ++rt)
                afh[rt] = *(const short8*)&ah[aoff0 + (rt << 9)];
            #pragma unroll
            for (int jt = 0; jt < 4; ++jt)
                bfh[jt] = *(const short8*)&bh[boff0 + (jt << 9)];
            #pragma unroll
            for (int rt = 0; rt < 4; ++rt)
                #pragma unroll
                for (int jt = 0; jt < 4; ++jt)
                    acc[rt][jt] = __builtin_amdgcn_mfma_f32_16x16x32_bf16(
                        afh[rt], bfh[jt], acc[rt][jt], 0, 0, 0);

            #pragma unroll
            for (int rt = 0; rt < 4; ++rt)
                afl[rt] = *(const short8*)&al[aoff0 + (rt << 9)];
            #pragma unroll
            for (int rt = 0; rt < 4; ++rt)
                #pragma unroll
                for (int jt = 0; jt < 4; ++jt)
                    acc[rt][jt] = __builtin_amdgcn_mfma_f32_16x16x32_bf16(
                        afl[rt], bfh[jt], acc[rt][jt], 0, 0, 0);

            #pragma unroll
            for (int jt = 0; jt < 4; ++jt)
                bfl[jt] = *(const short8*)&bl[boff0 + (jt << 9)];
            #pragma unroll
            for (int rt = 0; rt < 4; ++rt)
                #pragma unroll
                for (int jt = 0; jt < 4; ++jt)
                    acc[rt][jt] = __builtin_amdgcn_mfma_f32_16x16x32_bf16(
                        afh[rt], bfl[jt], acc[rt][jt], 0, 0, 0);
        }

        #pragma unroll
        for (int jt = 0; jt < 4; ++jt) {
            int c = ct * 128 + wx * 64 + jt * 16 + l15;
            float eec = ee[c];
            #pragma unroll
            for (int rt = 0; rt < 4; ++rt) {
                #pragma unroll
                for (int reg = 0; reg < 4; ++reg) {
                    float s = eec - 2.0f * acc[rt][jt][reg];
                    int slot = rt * 4 + reg;
                    if (s < bestv[slot]) {
                        best2v[slot] = bestv[slot];
                        bestv[slot] = s; besti[slot] = c;
                    } else {
                        best2v[slot] = fminf(best2v[slot], s);
                    }
                }
            }
        }
    }
#undef STAGE

    #pragma unroll
    for (int slot = 0; slot < 16; ++slot) {
        float bv = bestv[slot]; int bi = besti[slot]; float b2 = best2v[slot];
        #pragma unroll
        for (int off = 8; off >= 1; off >>= 1) {
            float ov  = __shfl_xor(bv, off, 16);
            int   oi  = __shfl_xor(bi, off, 16);
            float ov2 = __shfl_xor(b2, off, 16);
            float nm2 = fminf(fminf(b2, ov2), fmaxf(bv, ov));
            if (ov < bv) { bv = ov; bi = oi; }
            b2 = nm2;
        }
        bestv[slot] = bv; besti[slot] = bi; best2v[slot] = b2;
    }

    if (l15 == 0) {
        #pragma unroll
        for (int rt = 0; rt < 4; ++rt)
            #pragma unroll
            for (int reg = 0; reg < 4; ++reg) {
                int rloc2 = wy * 64 + rt * 16 + quad * 4 + reg;
                int slot = rt * 4 + reg;
                redv[wx][rloc2] = bestv[slot];
                red2[wx][rloc2] = best2v[slot];
                redi[wx][rloc2] = besti[slot];
            }
    }
    __syncthreads();
    if (tid < 128) {
        float v0 = redv[0][tid], v1 = redv[1][tid];
        float s0 = red2[0][tid], s1 = red2[1][tid];
        float m1, m2; int mi;
        if (v0 <= v1) { m1 = v0; mi = redi[0][tid]; m2 = fminf(fminf(s0, s1), v1); }
        else          { m1 = v1; mi = redi[1][tid]; m2 = fminf(fminf(s0, s1), v0); }
        long rowAbs = row0 + tid;
        ind_out[rowAbs] = (float)mi;
        if (m2 - m1 <= WINDOW) {
            int q = atomicAdd(qbase, 1);
            qbase[1 + q] = (int)rowAbs;
        }
    }
}

// ============================================================
// Kernel D (pass 2): exact fp32 rescan of ambiguous rows.
// ============================================================
__global__ __launch_bounds__(256) void pass2_kernel(
    const float* __restrict__ x, const float* __restrict__ embed,
    const float* __restrict__ ee, const int* __restrict__ qbase,
    float* __restrict__ ind_out)
{
    __shared__ float xs[256];
    __shared__ float sv[256];
    __shared__ int   si[256];
    const int tid = threadIdx.x;
    const int count = qbase[0];

    for (int qi = blockIdx.x; qi < count; qi += gridDim.x) {
        int row = qbase[1 + qi];
        __syncthreads();
        xs[tid] = x[(long)row * Dd + tid];
        __syncthreads();
        float bv = FLT_MAX; int bi = 0;
        for (int c = tid; c < Kk; c += 256) {
            const float* er = &embed[(long)c * Dd];
            float dot = 0.0f;
            for (int d = 0; d < Dd; ++d) dot += xs[d] * er[d];
            float s = ee[c] - 2.0f * dot;
            if (s < bv) { bv = s; bi = c; }
        }
        sv[tid] = bv; si[tid] = bi;
        __syncthreads();
        for (int off = 128; off >= 1; off >>= 1) {
            if (tid < off) {
                float v2 = sv[tid + off]; int i2 = si[tid + off];
                if (v2 < sv[tid] || (v2 == sv[tid] && i2 < si[tid])) {
                    sv[tid] = v2; si[tid] = i2;
                }
            }
            __syncthreads();
        }
        if (tid == 0) ind_out[row] = (float)si[0];
    }
}

// ============================================================
// Kernel E: quantize gather (pure BW, no atomics). One wave per row.
// ============================================================
__global__ __launch_bounds__(256) void quant_gather_kernel(
    const float* __restrict__ embed, const float* __restrict__ ind_f,
    float* __restrict__ quant)
{
    long row  = (long)blockIdx.x * 4 + (threadIdx.x >> 6);
    int  lane = threadIdx.x & 63;
    int  idx  = (int)ind_f[row];
    float4 ev = *(const float4*)&embed[(long)idx * Dd + lane * 4];
    *(float4*)&quant[row * Dd + lane * 4] = ev;
}

// ============================================================
// Kernel F: pull-based segmented sum. Block (k, s): scan strip s of ind,
// ballot-match code k, accumulate matching x rows in registers.
// ============================================================
template <int USE_ATOMIC>
__global__ __launch_bounds__(256) void segsum_kernel(
    const float* __restrict__ x, const float* __restrict__ ind_f,
    float* __restrict__ dst, float* __restrict__ counts)
{
    __shared__ float part[4][256];
    __shared__ float cnt_l[4];
    const int tid  = threadIdx.x;
    const int w    = tid >> 6;
    const int lane = tid & 63;
    const int k    = blockIdx.x >> 3;          // PARTS=8
    const int s    = blockIdx.x & 7;

    constexpr int STRIP = Nn / PARTS;          // 8192 rows
    constexpr int WAVE_ROWS = STRIP / 4;       // 2048 rows per wave
    const int base0 = s * STRIP + w * WAVE_ROWS;

    float4 acc = {0.f, 0.f, 0.f, 0.f};
    int cnt = 0;
    for (int win = 0; win < WAVE_ROWS; win += 64) {
        int idx = (int)ind_f[base0 + win + lane];
        unsigned long long m = __ballot(idx == k);
        cnt += __popcll(m);
        while (m) {
            int l = __ffsll((unsigned long long)m) - 1;
            m &= m - 1;
            long row = base0 + win + l;
            float4 v = *(const float4*)&x[row * Dd + lane * 4];
            acc.x += v.x; acc.y += v.y; acc.z += v.z; acc.w += v.w;
        }
    }
    *(float4*)&part[w][lane * 4] = acc;
    if (lane == 0) cnt_l[w] = (float)cnt;
    __syncthreads();
    float sum = part[0][tid] + part[1][tid] + part[2][tid] + part[3][tid];
    if (USE_ATOMIC) {
        if (sum != 0.0f) atomicAdd(&dst[(long)k * Dd + tid], sum);
    } else {
        dst[((long)s * Kk + k) * Dd + tid] = sum;
    }
    if (tid == 0)
        atomicAdd(&counts[k], cnt_l[0] + cnt_l[1] + cnt_l[2] + cnt_l[3]);
}

// ============================================================
// Kernel G: new_cluster_size + total (single block)
// ============================================================
__global__ __launch_bounds__(256) void ema_cs_kernel(
    const float* __restrict__ cs, const float* __restrict__ counts,
    float* __restrict__ ncs, float* __restrict__ total_ws)
{
    __shared__ float red[256];
    int tid = threadIdx.x;
    float s = 0.0f;
    #pragma unroll
    for (int i = 0; i < 8; ++i) {
        int k = tid + i * 256;
        float v = cs[k] * DECAY + OMD * counts[k];
        ncs[k] = v;
        s += v;
    }
    red[tid] = s;
    __syncthreads();
    #pragma unroll
    for (int off = 128; off >= 1; off >>= 1) {
        if (tid < off) red[tid] += red[tid + off];
        __syncthreads();
    }
    if (tid == 0) total_ws[0] = red[0];
}

// ============================================================
// Kernel H: combine partials -> embed_sum; nea; ne.
// ============================================================
__global__ __launch_bounds__(256) void nea_ne_kernel(
    const float* __restrict__ ea, const float* __restrict__ partials,
    int nparts, const float* __restrict__ ncs, const float* __restrict__ total_ws,
    float* __restrict__ nea, float* __restrict__ ne)
{
    long g = ((long)blockIdx.x * 256 + threadIdx.x) * 4;
    int  k = (int)(g >> 8);
    int  d = (int)(g & 255);

    float4 sv = {0.f, 0.f, 0.f, 0.f};
    for (int p = 0; p < nparts; ++p) {
        float4 pv = *(const float4*)&partials[((long)p * Kk + k) * Dd + d];
        sv.x += pv.x; sv.y += pv.y; sv.z += pv.z; sv.w += pv.w;
    }

    float4 av = *(const float4*)&ea[g];
    float4 out_nea;
    out_nea.x = av.x * DECAY + OMD * sv.x;
    out_nea.y = av.y * DECAY + OMD * sv.y;
    out_nea.z = av.z * DECAY + OMD * sv.z;
    out_nea.w = av.w * DECAY + OMD * sv.w;
    *(float4*)&nea[g] = out_nea;

    float total = total_ws[0];
    float sm = (ncs[k] + EPSF) / (total + EPSF * (float)Kk) * total;
    float inv = 1.0f / sm;
    float4 out_ne;
    out_ne.x = out_nea.x * inv;
    out_ne.y = out_nea.y * inv;
    out_ne.z = out_nea.z * inv;
    out_ne.w = out_nea.w * inv;
    *(float4*)&ne[g] = out_ne;
}

// ============================================================
extern "C" void kernel_launch(void* const* d_in, const int* in_sizes, int n_in,
                              void* d_out, int out_size, void* d_ws, size_t ws_size,
                              hipStream_t stream)
{
    const float* x     = (const float*)d_in[0];
    const float* embed = (const float*)d_in[1];
    const float* cs    = (const float*)d_in[2];
    const float* ea    = (const float*)d_in[3];

    float* out   = (float*)d_out;
    float* quant = out + OUT_QUANT;
    float* ind_f = out + OUT_IND;
    float* ncs   = out + OUT_NCS;
    float* nea   = out + OUT_NEA;
    float* ne    = out + OUT_NE;

    float* ws     = (float*)d_ws;
    float* counts = ws + WS_COUNTS;
    float* total  = ws + WS_TOTAL;
    float* ee     = ws + WS_EE;
    float* big    = ws + WS_BIG;     // embed_sum (atomic) or partials (ws path)

    // scratch inside d_out
    ushort* x_hi = (ushort*)(out + OUT_QUANT);
    ushort* x_lo = (ushort*)(out + OUT_QUANT + Nn * (Dd / 2));
    ushort* e_hi = (ushort*)(out + OUT_NEA);
    ushort* e_lo = (ushort*)(out + OUT_NEA + Kk * (Dd / 2));
    int*    qb   = (int*)(out + OUT_NE);

    const size_t need_partials =
        (size_t)(WS_BIG + (long)PARTS * Kk * Dd) * sizeof(float) + 1024;
    const bool use_ws_partials = ws_size >= need_partials;

    hipMemsetAsync(counts, 0, Kk * sizeof(float), stream);
    hipMemsetAsync(qb, 0, sizeof(int), stream);
    if (!use_ws_partials)
        hipMemsetAsync(big, 0, (size_t)Kk * Dd * sizeof(float), stream);

    convert_x_kernel<<<(Nn * Dd / 4) / 256, 256, 0, stream>>>(x, x_hi, x_lo);
    convert_e_kernel<<<Kk / 4, 256, 0, stream>>>(embed, e_hi, e_lo, ee);
    pass1_kernel<<<Nn / 128, 256, 0, stream>>>(x_hi, x_lo, e_hi, e_lo, ee, ind_f, qb);
    pass2_kernel<<<256, 256, 0, stream>>>(x, embed, ee, qb, ind_f);
    quant_gather_kernel<<<Nn / 4, 256, 0, stream>>>(embed, ind_f, quant);
    if (use_ws_partials)
        segsum_kernel<0><<<Kk * PARTS, 256, 0, stream>>>(x, ind_f, big, counts);
    else
        segsum_kernel<1><<<Kk * PARTS, 256, 0, stream>>>(x, ind_f, big, counts);
    ema_cs_kernel<<<1, 256, 0, stream>>>(cs, counts, ncs, total);
    nea_ne_kernel<<<(Kk * Dd / 4) / 256, 256, 0, stream>>>(
        ea, big, use_ws_partials ? PARTS : 1, ncs, total, nea, ne);
}

// Round 2
// 542.408 us; speedup vs baseline: 1.2563x; 1.0330x over previous
//
#include <hip/hip_runtime.h>
#include <hip/hip_bf16.h>
#include <float.h>

#define DECAY 0.99f
#define OMD   0.01f
#define EPSF  1e-6f

constexpr int Bb = 8, Ss = 8192, Dd = 256, Kk = 2048;
constexpr int Nn = Bb * Ss;                 // 65536 rows

// ---- output layout (floats) ----
constexpr long OUT_QUANT = 0;                         // 16777216 floats
constexpr long OUT_IND   = (long)Nn * Dd;             // 16777216
constexpr long OUT_NCS   = OUT_IND + Nn;              // 16842752
constexpr long OUT_NEA   = OUT_NCS + Kk;              // 16844800
constexpr long OUT_NE    = OUT_NEA + (long)Kk * Dd;   // 17369088

// ---- workspace layout (floats) ----
constexpr long WS_COUNTS = 0;                         // K
constexpr long WS_TOTAL  = 2048;                      // 1
constexpr long WS_EE     = 2112;                      // K
constexpr long WS_BIG    = 4160;                      // embed_sum (atomic path)
                                                      // or 8 partials (ws path)
constexpr int  PARTS     = 8;                         // strip split for segsum

typedef __attribute__((ext_vector_type(8))) short short8;
typedef __attribute__((ext_vector_type(4))) float floatx4;

// split-bf16 certainty window: rows whose approx top-2 gap <= WINDOW get an
// exact fp32 rescan in pass 2.
#define WINDOW 0.0625f

// async global->LDS, 16B per lane, LDS dest = wave-uniform base + lane*16
__device__ __forceinline__ void gl_lds(const ushort* g, ushort* l)
{
    __builtin_amdgcn_global_load_lds(
        (const __attribute__((address_space(1))) void*)g,
        (__attribute__((address_space(3))) void*)l,
        16, 0, 0);
}

// ============================================================
// Kernel A: x -> x_hi(bf16), x_lo = bf16(x - x_hi)
// ============================================================
__global__ __launch_bounds__(256) void convert_x_kernel(
    const float* __restrict__ x, ushort* __restrict__ x_hi, ushort* __restrict__ x_lo)
{
    long base = ((long)blockIdx.x * 256 + threadIdx.x) * 4;
    float4 v = *(const float4*)&x[base];
    float vv[4] = {v.x, v.y, v.z, v.w};
    ushort hh[4], ll[4];
    #pragma unroll
    for (int i = 0; i < 4; ++i) {
        __hip_bfloat16 hb = __float2bfloat16(vv[i]);
        float r = vv[i] - __bfloat162float(hb);
        __hip_bfloat16 lb = __float2bfloat16(r);
        hh[i] = *(ushort*)&hb; ll[i] = *(ushort*)&lb;
    }
    ushort4 h; h.x = hh[0]; h.y = hh[1]; h.z = hh[2]; h.w = hh[3];
    ushort4 l; l.x = ll[0]; l.y = ll[1]; l.z = ll[2]; l.w = ll[3];
    *(ushort4*)&x_hi[base] = h;
    *(ushort4*)&x_lo[base] = l;
}

// ============================================================
// Kernel B: embed -> e_hi, e_lo and ee[k] = sum_d embed[k][d]^2
// ============================================================
__global__ __launch_bounds__(256) void convert_e_kernel(
    const float* __restrict__ embed, ushort* __restrict__ e_hi,
    ushort* __restrict__ e_lo, float* __restrict__ ee)
{
    int row  = blockIdx.x * 4 + (threadIdx.x >> 6);
    int lane = threadIdx.x & 63;
    long base = (long)row * Dd + lane * 4;
    float4 v = *(const float4*)&embed[base];
    float vv[4] = {v.x, v.y, v.z, v.w};
    ushort hh[4], ll[4];
    float s = 0.0f;
    #pragma unroll
    for (int i = 0; i < 4; ++i) {
        s += vv[i] * vv[i];
        __hip_bfloat16 hb = __float2bfloat16(vv[i]);
        float r = vv[i] - __bfloat162float(hb);
        __hip_bfloat16 lb = __float2bfloat16(r);
        hh[i] = *(ushort*)&hb; ll[i] = *(ushort*)&lb;
    }
    ushort4 h; h.x = hh[0]; h.y = hh[1]; h.z = hh[2]; h.w = hh[3];
    ushort4 l; l.x = ll[0]; l.y = ll[1]; l.z = ll[2]; l.w = ll[3];
    *(ushort4*)&e_hi[base] = h;
    *(ushort4*)&e_lo[base] = l;
    #pragma unroll
    for (int off = 32; off >= 1; off >>= 1)
        s += __shfl_xor(s, off, 64);
    if (lane == 0) ee[row] = s;
}

// ============================================================
// Kernel C (pass 1): MFMA split-bf16 fused GEMM + top-2 argmin.
//
// v3 (this round): double-buffered 2-phase pipeline (T3/T4 minimum recipe):
//   per tile t: STAGE(t+1 -> buf^1); s_waitcnt vmcnt(8)  [t+1's 8 loads stay
//   in flight across the barrier]; raw s_barrier; ds_read+MFMA from buf;
//   raw s_barrier.  Safety: the last ds_read of each tile feeds an MFMA in
//   the same tile, so lgkmcnt drains to 0 before the end barrier -> no
//   read-vs-overwrite race with the next tile's global_load_lds.
//   setprio(1) around each MFMA cluster (T5).
// ============================================================
__global__ __attribute__((amdgpu_waves_per_eu(2, 2))) __launch_bounds__(256)
void pass1_kernel(
    const ushort* __restrict__ x_hi, const ushort* __restrict__ x_lo,
    const ushort* __restrict__ e_hi, const ushort* __restrict__ e_lo,
    const float* __restrict__ ee, float* __restrict__ ind_out,
    int* __restrict__ qbase)
{
    // 4 tiles of [128 rows][32 bf16] = 8KB each, double-buffered
    __shared__ __attribute__((aligned(16))) ushort ah[2][4096];
    __shared__ __attribute__((aligned(16))) ushort al[2][4096];
    __shared__ __attribute__((aligned(16))) ushort bh[2][4096];
    __shared__ __attribute__((aligned(16))) ushort bl[2][4096];
    __shared__ float  redv[2][128];
    __shared__ float  red2[2][128];
    __shared__ int    redi[2][128];

    const int tid  = threadIdx.x;
    const int lane = tid & 63;
    const int quad = lane >> 4;
    const int l15  = lane & 15;
    const int w    = tid >> 6;
    const int wy   = w >> 1;
    const int wx   = w & 1;
    const long row0 = (long)blockIdx.x * 128;

    // staging source pre-swizzle (per-lane, seg-invariant)
    const int rloc   = lane >> 2;
    const int cchunk = (lane & 3) ^ ((rloc >> 1) & 3);
    const int gcoff  = rloc * 256 + cchunk * 8;   // ushort offset from (seg row0, kcol)

    // fragment read swizzle
    const int sread = (l15 >> 1) & 3;
    const int aoff0 = ((wy * 64 + l15) << 5) + ((quad ^ sread) << 3);
    const int boff0 = ((wx * 64 + l15) << 5) + ((quad ^ sread) << 3);

    float bestv[16], best2v[16];
    int   besti[16];
    #pragma unroll
    for (int i = 0; i < 16; ++i) { bestv[i] = FLT_MAX; best2v[i] = FLT_MAX; besti[i] = 0; }

    // 8 gl_lds per wave per tile: 2 segments (w, w+4) x 4 buffers
#define STAGE(b, ctn, kcn)                                                       \
    do {                                                                         \
        const int  kcol_ = (kcn) * 32;                                           \
        const long brow_ = (long)(ctn) * 128;                                    \
        gl_lds(&x_hi[((row0 + w * 16) << 8) + kcol_ + gcoff],       &ah[b][w * 512]);       \
        gl_lds(&x_hi[((row0 + (w + 4) * 16) << 8) + kcol_ + gcoff], &ah[b][(w + 4) * 512]); \
        gl_lds(&x_lo[((row0 + w * 16) << 8) + kcol_ + gcoff],       &al[b][w * 512]);       \
        gl_lds(&x_lo[((row0 + (w + 4) * 16) << 8) + kcol_ + gcoff], &al[b][(w + 4) * 512]); \
        gl_lds(&e_hi[((brow_ + w * 16) << 8) + kcol_ + gcoff],       &bh[b][w * 512]);       \
        gl_lds(&e_hi[((brow_ + (w + 4) * 16) << 8) + kcol_ + gcoff], &bh[b][(w + 4) * 512]); \
        gl_lds(&e_lo[((brow_ + w * 16) << 8) + kcol_ + gcoff],       &bl[b][w * 512]);       \
        gl_lds(&e_lo[((brow_ + (w + 4) * 16) << 8) + kcol_ + gcoff], &bl[b][(w + 4) * 512]); \
    } while (0)

    STAGE(0, 0, 0);   // prologue: tile 0 into buf 0

    for (int ct = 0; ct < 16; ++ct) {
        floatx4 acc[4][4];
        #pragma unroll
        for (int rt = 0; rt < 4; ++rt)
            #pragma unroll
            for (int jt = 0; jt < 4; ++jt)
                acc[rt][jt] = (floatx4){0.f, 0.f, 0.f, 0.f};

        for (int kc = 0; kc < 8; ++kc) {
            const int t   = ct * 8 + kc;
            const int cur = t & 1;
            const int tn  = (t + 1) & 127;        // wraps: last tile re-stages tile 0 (benign)

            STAGE(cur ^ 1, tn >> 3, tn & 7);      // prefetch next tile
            asm volatile("s_waitcnt vmcnt(8)" ::: "memory");  // my tile-t loads landed
            __builtin_amdgcn_s_barrier();                      // everyone's landed
            __builtin_amdgcn_sched_barrier(0);

            short8 afh[4], bfh[4], afl[4], bfl[4];
            #pragma unroll
            for (int rt = 0; rt < 4; ++rt)
                afh[rt] = *(const short8*)&ah[cur][aoff0 + (rt << 9)];
            #pragma unroll
            for (int jt = 0; jt < 4; ++jt)
                bfh[jt] = *(const short8*)&bh[cur][boff0 + (jt << 9)];
            __builtin_amdgcn_s_setprio(1);
            #pragma unroll
            for (int rt = 0; rt < 4; ++rt)
                #pragma unroll
                for (int jt = 0; jt < 4; ++jt)
                    acc[rt][jt] = __builtin_amdgcn_mfma_f32_16x16x32_bf16(
                        afh[rt], bfh[jt], acc[rt][jt], 0, 0, 0);
            __builtin_amdgcn_s_setprio(0);

            #pragma unroll
            for (int rt = 0; rt < 4; ++rt)
                afl[rt] = *(const short8*)&al[cur][aoff0 + (rt << 9)];
            __builtin_amdgcn_s_setprio(1);
            #pragma unroll
            for (int rt = 0; rt < 4; ++rt)
                #pragma unroll
                for (int jt = 0; jt < 4; ++jt)
                    acc[rt][jt] = __builtin_amdgcn_mfma_f32_16x16x32_bf16(
                        afl[rt], bfh[jt], acc[rt][jt], 0, 0, 0);
            __builtin_amdgcn_s_setprio(0);

            #pragma unroll
            for (int jt = 0; jt < 4; ++jt)
                bfl[jt] = *(const short8*)&bl[cur][boff0 + (jt << 9)];
            __builtin_amdgcn_s_setprio(1);
            #pragma unroll
            for (int rt = 0; rt < 4; ++rt)
                #pragma unroll
                for (int jt = 0; jt < 4; ++jt)
                    acc[rt][jt] = __builtin_amdgcn_mfma_f32_16x16x32_bf16(
                        afh[rt], bfl[jt], acc[rt][jt], 0, 0, 0);
            __builtin_amdgcn_s_setprio(0);

            __builtin_amdgcn_sched_barrier(0);    // pin ds_reads inside phase
            __builtin_amdgcn_s_barrier();         // reads done before next overwrite
        }

        #pragma unroll
        for (int jt = 0; jt < 4; ++jt) {
            int c = ct * 128 + wx * 64 + jt * 16 + l15;
            float eec = ee[c];
            #pragma unroll
            for (int rt = 0; rt < 4; ++rt) {
                #pragma unroll
                for (int reg = 0; reg < 4; ++reg) {
                    float s = eec - 2.0f * acc[rt][jt][reg];
                    int slot = rt * 4 + reg;
                    if (s < bestv[slot]) {
                        best2v[slot] = bestv[slot];
                        bestv[slot] = s; besti[slot] = c;
                    } else {
                        best2v[slot] = fminf(best2v[slot], s);
                    }
                }
            }
        }
    }
#undef STAGE
    asm volatile("s_waitcnt vmcnt(0)" ::: "memory");  // drain wraparound prefetch

    #pragma unroll
    for (int slot = 0; slot < 16; ++slot) {
        float bv = bestv[slot]; int bi = besti[slot]; float b2 = best2v[slot];
        #pragma unroll
        for (int off = 8; off >= 1; off >>= 1) {
            float ov  = __shfl_xor(bv, off, 16);
            int   oi  = __shfl_xor(bi, off, 16);
            float ov2 = __shfl_xor(b2, off, 16);
            float nm2 = fminf(fminf(b2, ov2), fmaxf(bv, ov));
            if (ov < bv) { bv = ov; bi = oi; }
            b2 = nm2;
        }
        bestv[slot] = bv; besti[slot] = bi; best2v[slot] = b2;
    }

    if (l15 == 0) {
        #pragma unroll
        for (int rt = 0; rt < 4; ++rt)
            #pragma unroll
            for (int reg = 0; reg < 4; ++reg) {
                int rloc2 = wy * 64 + rt * 16 + quad * 4 + reg;
                int slot = rt * 4 + reg;
                redv[wx][rloc2] = bestv[slot];
                red2[wx][rloc2] = best2v[slot];
                redi[wx][rloc2] = besti[slot];
            }
    }
    __syncthreads();
    if (tid < 128) {
        float v0 = redv[0][tid], v1 = redv[1][tid];
        float s0 = red2[0][tid], s1 = red2[1][tid];
        float m1, m2; int mi;
        if (v0 <= v1) { m1 = v0; mi = redi[0][tid]; m2 = fminf(fminf(s0, s1), v1); }
        else          { m1 = v1; mi = redi[1][tid]; m2 = fminf(fminf(s0, s1), v0); }
        long rowAbs = row0 + tid;
        ind_out[rowAbs] = (float)mi;
        if (m2 - m1 <= WINDOW) {
            int q = atomicAdd(qbase, 1);
            qbase[1 + q] = (int)rowAbs;
        }
    }
}

// ============================================================
// Kernel D (pass 2): exact fp32 rescan of ambiguous rows.
// v2: batch 8 rows per sweep -> embed streamed once per 8 rows (8x less L2
// traffic), float4 loads. Same partitioning + comparator as v1 -> identical
// indices (lowest-index tie-break preserved).
// ============================================================
constexpr int RB = 8;
__global__ __launch_bounds__(256) void pass2_kernel(
    const float* __restrict__ x, const float* __restrict__ embed,
    const float* __restrict__ ee, const int* __restrict__ qbase,
    float* __restrict__ ind_out)
{
    __shared__ float xs[RB][256];
    __shared__ float sv[RB][256];
    __shared__ int   si[RB][256];
    const int tid = threadIdx.x;
    const int count = qbase[0];

    for (int q0 = blockIdx.x * RB; q0 < count; q0 += gridDim.x * RB) {
        const int nr = (count - q0 < RB) ? (count - q0) : RB;
        __syncthreads();
        for (int r = 0; r < nr; ++r)
            xs[r][tid] = x[(long)qbase[1 + q0 + r] * Dd + tid];
        __syncthreads();

        float bv[RB]; int bi[RB];
        #pragma unroll
        for (int r = 0; r < RB; ++r) { bv[r] = FLT_MAX; bi[r] = 0; }

        for (int i = 0; i < Kk / 256; ++i) {
            const int c = i * 256 + tid;
            const float4* er = (const float4*)&embed[(long)c * Dd];
            float dot[RB];
            #pragma unroll
            for (int r = 0; r < RB; ++r) dot[r] = 0.0f;
            for (int d = 0; d < Dd / 4; ++d) {
                float4 e4 = er[d];
                #pragma unroll
                for (int r = 0; r < RB; ++r) {
                    float4 x4 = *(const float4*)&xs[r][d * 4];
                    dot[r] += e4.x * x4.x + e4.y * x4.y + e4.z * x4.z + e4.w * x4.w;
                }
            }
            float eec = ee[c];
            #pragma unroll
            for (int r = 0; r < RB; ++r) {
                float s = eec - 2.0f * dot[r];
                if (s < bv[r]) { bv[r] = s; bi[r] = c; }
            }
        }

        #pragma unroll
        for (int r = 0; r < RB; ++r) { sv[r][tid] = bv[r]; si[r][tid] = bi[r]; }
        __syncthreads();
        for (int off = 128; off >= 1; off >>= 1) {
            if (tid < off) {
                #pragma unroll
                for (int r = 0; r < RB; ++r) {
                    float v2 = sv[r][tid + off]; int i2 = si[r][tid + off];
                    if (v2 < sv[r][tid] || (v2 == sv[r][tid] && i2 < si[r][tid])) {
                        sv[r][tid] = v2; si[r][tid] = i2;
                    }
                }
            }
            __syncthreads();
        }
        if (tid < nr)
            ind_out[qbase[1 + q0 + tid]] = (float)si[tid][0];
        __syncthreads();
    }
}

// ============================================================
// Kernel E: quantize gather (pure BW, no atomics). One wave per row.
// ============================================================
__global__ __launch_bounds__(256) void quant_gather_kernel(
    const float* __restrict__ embed, const float* __restrict__ ind_f,
    float* __restrict__ quant)
{
    long row  = (long)blockIdx.x * 4 + (threadIdx.x >> 6);
    int  lane = threadIdx.x & 63;
    int  idx  = (int)ind_f[row];
    float4 ev = *(const float4*)&embed[(long)idx * Dd + lane * 4];
    *(float4*)&quant[row * Dd + lane * 4] = ev;
}

// ============================================================
// Kernel F: pull-based segmented sum. Block (k, s): scan strip s of ind,
// ballot-match code k, accumulate matching x rows in registers.
// ============================================================
template <int USE_ATOMIC>
__global__ __launch_bounds__(256) void segsum_kernel(
    const float* __restrict__ x, const float* __restrict__ ind_f,
    float* __restrict__ dst, float* __restrict__ counts)
{
    __shared__ float part[4][256];
    __shared__ float cnt_l[4];
    const int tid  = threadIdx.x;
    const int w    = tid >> 6;
    const int lane = tid & 63;
    const int k    = blockIdx.x >> 3;          // PARTS=8
    const int s    = blockIdx.x & 7;

    constexpr int STRIP = Nn / PARTS;          // 8192 rows
    constexpr int WAVE_ROWS = STRIP / 4;       // 2048 rows per wave
    const int base0 = s * STRIP + w * WAVE_ROWS;

    float4 acc = {0.f, 0.f, 0.f, 0.f};
    int cnt = 0;
    for (int win = 0; win < WAVE_ROWS; win += 64) {
        int idx = (int)ind_f[base0 + win + lane];
        unsigned long long m = __ballot(idx == k);
        cnt += __popcll(m);
        while (m) {
            int l = __ffsll((unsigned long long)m) - 1;
            m &= m - 1;
            long row = base0 + win + l;
            float4 v = *(const float4*)&x[row * Dd + lane * 4];
            acc.x += v.x; acc.y += v.y; acc.z += v.z; acc.w += v.w;
        }
    }
    *(float4*)&part[w][lane * 4] = acc;
    if (lane == 0) cnt_l[w] = (float)cnt;
    __syncthreads();
    float sum = part[0][tid] + part[1][tid] + part[2][tid] + part[3][tid];
    if (USE_ATOMIC) {
        if (sum != 0.0f) atomicAdd(&dst[(long)k * Dd + tid], sum);
    } else {
        dst[((long)s * Kk + k) * Dd + tid] = sum;
    }
    if (tid == 0)
        atomicAdd(&counts[k], cnt_l[0] + cnt_l[1] + cnt_l[2] + cnt_l[3]);
}

// ============================================================
// Kernel G: new_cluster_size + total (single block)
// ============================================================
__global__ __launch_bounds__(256) void ema_cs_kernel(
    const float* __restrict__ cs, const float* __restrict__ counts,
    float* __restrict__ ncs, float* __restrict__ total_ws)
{
    __shared__ float red[256];
    int tid = threadIdx.x;
    float s = 0.0f;
    #pragma unroll
    for (int i = 0; i < 8; ++i) {
        int k = tid + i * 256;
        float v = cs[k] * DECAY + OMD * counts[k];
        ncs[k] = v;
        s += v;
    }
    red[tid] = s;
    __syncthreads();
    #pragma unroll
    for (int off = 128; off >= 1; off >>= 1) {
        if (tid < off) red[tid] += red[tid + off];
        __syncthreads();
    }
    if (tid == 0) total_ws[0] = red[0];
}

// ============================================================
// Kernel H: combine partials -> embed_sum; nea; ne.
// ============================================================
__global__ __launch_bounds__(256) void nea_ne_kernel(
    const float* __restrict__ ea, const float* __restrict__ partials,
    int nparts, const float* __restrict__ ncs, const float* __restrict__ total_ws,
    float* __restrict__ nea, float* __restrict__ ne)
{
    long g = ((long)blockIdx.x * 256 + threadIdx.x) * 4;
    int  k = (int)(g >> 8);
    int  d = (int)(g & 255);

    float4 sv = {0.f, 0.f, 0.f, 0.f};
    for (int p = 0; p < nparts; ++p) {
        float4 pv = *(const float4*)&partials[((long)p * Kk + k) * Dd + d];
        sv.x += pv.x; sv.y += pv.y; sv.z += pv.z; sv.w += pv.w;
    }

    float4 av = *(const float4*)&ea[g];
    float4 out_nea;
    out_nea.x = av.x * DECAY + OMD * sv.x;
    out_nea.y = av.y * DECAY + OMD * sv.y;
    out_nea.z = av.z * DECAY + OMD * sv.z;
    out_nea.w = av.w * DECAY + OMD * sv.w;
    *(float4*)&nea[g] = out_nea;

    float total = total_ws[0];
    float sm = (ncs[k] + EPSF) / (total + EPSF * (float)Kk) * total;
    float inv = 1.0f / sm;
    float4 out_ne;
    out_ne.x = out_nea.x * inv;
    out_ne.y = out_nea.y * inv;
    out_ne.z = out_nea.z * inv;
    out_ne.w = out_nea.w * inv;
    *(float4*)&ne[g] = out_ne;
}

// ============================================================
extern "C" void kernel_launch(void* const* d_in, const int* in_sizes, int n_in,
                              void* d_out, int out_size, void* d_ws, size_t ws_size,
                              hipStream_t stream)
{
    const float* x     = (const float*)d_in[0];
    const float* embed = (const float*)d_in[1];
    const float* cs    = (const float*)d_in[2];
    const float* ea    = (const float*)d_in[3];

    float* out   = (float*)d_out;
    float* quant = out + OUT_QUANT;
    float* ind_f = out + OUT_IND;
    float* ncs   = out + OUT_NCS;
    float* nea   = out + OUT_NEA;
    float* ne    = out + OUT_NE;

    float* ws     = (float*)d_ws;
    float* counts = ws + WS_COUNTS;
    float* total  = ws + WS_TOTAL;
    float* ee     = ws + WS_EE;
    float* big    = ws + WS_BIG;     // embed_sum (atomic) or partials (ws path)

    // scratch inside d_out
    ushort* x_hi = (ushort*)(out + OUT_QUANT);
    ushort* x_lo = (ushort*)(out + OUT_QUANT + Nn * (Dd / 2));
    ushort* e_hi = (ushort*)(out + OUT_NEA);
    ushort* e_lo = (ushort*)(out + OUT_NEA + Kk * (Dd / 2));
    int*    qb   = (int*)(out + OUT_NE);

    const size_t need_partials =
        (size_t)(WS_BIG + (long)PARTS * Kk * Dd) * sizeof(float) + 1024;
    const bool use_ws_partials = ws_size >= need_partials;

    hipMemsetAsync(counts, 0, Kk * sizeof(float), stream);
    hipMemsetAsync(qb, 0, sizeof(int), stream);
    if (!use_ws_partials)
        hipMemsetAsync(big, 0, (size_t)Kk * Dd * sizeof(float), stream);

    convert_x_kernel<<<(Nn * Dd / 4) / 256, 256, 0, stream>>>(x, x_hi, x_lo);
    convert_e_kernel<<<Kk / 4, 256, 0, stream>>>(embed, e_hi, e_lo, ee);
    pass1_kernel<<<Nn / 128, 256, 0, stream>>>(x_hi, x_lo, e_hi, e_lo, ee, ind_f, qb);
    pass2_kernel<<<256, 256, 0, stream>>>(x, embed, ee, qb, ind_f);
    quant_gather_kernel<<<Nn / 4, 256, 0, stream>>>(embed, ind_f, quant);
    if (use_ws_partials)
        segsum_kernel<0><<<Kk * PARTS, 256, 0, stream>>>(x, ind_f, big, counts);
    else
        segsum_kernel<1><<<Kk * PARTS, 256, 0, stream>>>(x, ind_f, big, counts);
    ema_cs_kernel<<<1, 256, 0, stream>>>(cs, counts, ncs, total);
    nea_ne_kernel<<<(Kk * Dd / 4) / 256, 256, 0, stream>>>(
        ea, big, use_ws_partials ? PARTS : 1, ncs, total, nea, ne);
}

// Round 3
// 487.557 us; speedup vs baseline: 1.3977x; 1.1125x over previous
//
#include <hip/hip_runtime.h>
#include <hip/hip_bf16.h>
#include <float.h>

#define DECAY 0.99f
#define OMD   0.01f
#define EPSF  1e-6f

constexpr int Bb = 8, Ss = 8192, Dd = 256, Kk = 2048;
constexpr int Nn = Bb * Ss;                 // 65536 rows

// ---- output layout (floats) ----
constexpr long OUT_QUANT = 0;                         // 16777216 floats
constexpr long OUT_IND   = (long)Nn * Dd;             // 16777216
constexpr long OUT_NCS   = OUT_IND + Nn;              // 16842752
constexpr long OUT_NEA   = OUT_NCS + Kk;              // 16844800
constexpr long OUT_NE    = OUT_NEA + (long)Kk * Dd;   // 17369088

// ---- workspace layout (floats) ----
constexpr long WS_COUNTS = 0;                         // K
constexpr long WS_TOTAL  = 2048;                      // 1
constexpr long WS_EE     = 2112;                      // K
constexpr long WS_BIG    = 4160;                      // embed_sum (atomic path)
                                                      // or 8 partials (ws path)
constexpr int  PARTS     = 8;                         // strip split for segsum
constexpr int  CODES     = 8;                         // codes per segsum block

typedef __attribute__((ext_vector_type(8))) short short8;
typedef __attribute__((ext_vector_type(4))) float floatx4;

// split-bf16 certainty window: rows whose approx top-2 gap <= WINDOW get an
// exact fp32 rescan in pass 2.
#define WINDOW 0.0625f

// async global->LDS, 16B per lane, LDS dest = wave-uniform base + lane*16
__device__ __forceinline__ void gl_lds(const ushort* g, ushort* l)
{
    __builtin_amdgcn_global_load_lds(
        (const __attribute__((address_space(1))) void*)g,
        (__attribute__((address_space(3))) void*)l,
        16, 0, 0);
}

// ============================================================
// Kernel A: x -> x_hi(bf16), x_lo = bf16(x - x_hi)
// ============================================================
__global__ __launch_bounds__(256) void convert_x_kernel(
    const float* __restrict__ x, ushort* __restrict__ x_hi, ushort* __restrict__ x_lo)
{
    long base = ((long)blockIdx.x * 256 + threadIdx.x) * 4;
    float4 v = *(const float4*)&x[base];
    float vv[4] = {v.x, v.y, v.z, v.w};
    ushort hh[4], ll[4];
    #pragma unroll
    for (int i = 0; i < 4; ++i) {
        __hip_bfloat16 hb = __float2bfloat16(vv[i]);
        float r = vv[i] - __bfloat162float(hb);
        __hip_bfloat16 lb = __float2bfloat16(r);
        hh[i] = *(ushort*)&hb; ll[i] = *(ushort*)&lb;
    }
    ushort4 h; h.x = hh[0]; h.y = hh[1]; h.z = hh[2]; h.w = hh[3];
    ushort4 l; l.x = ll[0]; l.y = ll[1]; l.z = ll[2]; l.w = ll[3];
    *(ushort4*)&x_hi[base] = h;
    *(ushort4*)&x_lo[base] = l;
}

// ============================================================
// Kernel B: embed -> e_hi, e_lo and ee[k] = sum_d embed[k][d]^2
// ============================================================
__global__ __launch_bounds__(256) void convert_e_kernel(
    const float* __restrict__ embed, ushort* __restrict__ e_hi,
    ushort* __restrict__ e_lo, float* __restrict__ ee)
{
    int row  = blockIdx.x * 4 + (threadIdx.x >> 6);
    int lane = threadIdx.x & 63;
    long base = (long)row * Dd + lane * 4;
    float4 v = *(const float4*)&embed[base];
    float vv[4] = {v.x, v.y, v.z, v.w};
    ushort hh[4], ll[4];
    float s = 0.0f;
    #pragma unroll
    for (int i = 0; i < 4; ++i) {
        s += vv[i] * vv[i];
        __hip_bfloat16 hb = __float2bfloat16(vv[i]);
        float r = vv[i] - __bfloat162float(hb);
        __hip_bfloat16 lb = __float2bfloat16(r);
        hh[i] = *(ushort*)&hb; ll[i] = *(ushort*)&lb;
    }
    ushort4 h; h.x = hh[0]; h.y = hh[1]; h.z = hh[2]; h.w = hh[3];
    ushort4 l; l.x = ll[0]; l.y = ll[1]; l.z = ll[2]; l.w = ll[3];
    *(ushort4*)&e_hi[base] = h;
    *(ushort4*)&e_lo[base] = l;
    #pragma unroll
    for (int off = 32; off >= 1; off >>= 1)
        s += __shfl_xor(s, off, 64);
    if (lane == 0) ee[row] = s;
}

// ============================================================
// Kernel C (pass 1): MFMA split-bf16 fused GEMM + top-2 argmin.
//
// v4 (this round): revert round-2 explicit pipeline (regressed: barriers +
// sched_barrier pins defeated compiler scheduling; m114-style implicit
// 2-block overlap already covers it). Instead attack HBM traffic: CT=256
// codes per tile (was 128) -> x slices re-staged K/CT = 8x instead of 16x.
// Logical x re-read traffic halves (FETCH ~547MB -> ~300MB) and each
// stage-drain now amortizes over 96 MFMAs instead of 48.
// acc = 4x8 f32x4 = 128 VGPRs; b-fragments loaded per-jt (not held) to
// stay within the 2-waves/SIMD 256-VGPR budget.
// ============================================================
__global__ __attribute__((amdgpu_waves_per_eu(2, 2))) __launch_bounds__(256)
void pass1_kernel(
    const ushort* __restrict__ x_hi, const ushort* __restrict__ x_lo,
    const ushort* __restrict__ e_hi, const ushort* __restrict__ e_lo,
    const float* __restrict__ ee, float* __restrict__ ind_out,
    int* __restrict__ qbase)
{
    // a tiles: [128 rows][32 cols] = 8KB each; b tiles: [256 codes][32] = 16KB each
    __shared__ __attribute__((aligned(16))) ushort ah[128 * 32];
    __shared__ __attribute__((aligned(16))) ushort al[128 * 32];
    __shared__ __attribute__((aligned(16))) ushort bh[256 * 32];
    __shared__ __attribute__((aligned(16))) ushort bl[256 * 32];
    __shared__ float  redv[2][128];
    __shared__ float  red2[2][128];
    __shared__ int    redi[2][128];

    const int tid  = threadIdx.x;
    const int lane = tid & 63;
    const int quad = lane >> 4;
    const int l15  = lane & 15;
    const int w    = tid >> 6;
    const int wy   = w >> 1;
    const int wx   = w & 1;
    const long row0 = (long)blockIdx.x * 128;

    // staging source pre-swizzle (per-lane, segment-invariant):
    // within a 16-row segment, lane covers (rloc = lane>>2, slot = lane&3);
    // slot s must hold chunk s ^ ((row>>1)&3) = s ^ ((rloc>>1)&3).
    const int rloc   = lane >> 2;
    const int cchunk = (lane & 3) ^ ((rloc >> 1) & 3);
    const int gcoff  = rloc * 256 + cchunk * 8;   // ushort offset from (seg row0, kcol)

    // fragment read swizzle: row = ...+l15 -> (row>>1)&3 = (l15>>1)&3
    const int sread = (l15 >> 1) & 3;
    const int aoff0 = ((wy * 64 + l15) << 5) + ((quad ^ sread) << 3);
    const int boff0 = ((wx * 128 + l15) << 5) + ((quad ^ sread) << 3);

    float bestv[16], best2v[16];
    int   besti[16];
    #pragma unroll
    for (int i = 0; i < 16; ++i) { bestv[i] = FLT_MAX; best2v[i] = FLT_MAX; besti[i] = 0; }

    for (int ct = 0; ct < Kk / 256; ++ct) {
        floatx4 acc[4][8];
        #pragma unroll
        for (int rt = 0; rt < 4; ++rt)
            #pragma unroll
            for (int jt = 0; jt < 8; ++jt)
                acc[rt][jt] = (floatx4){0.f, 0.f, 0.f, 0.f};

        const long brow = (long)ct * 256;

        for (int kc = 0; kc < 8; ++kc) {
            const int kcol = kc * 32;

            __syncthreads();   // prior phase's fragment reads done
            // a: wave w stages 16-row segments {w, w+4} of 8
            gl_lds(&x_hi[((row0 + w * 16) << 8) + kcol + gcoff],       &ah[w * 512]);
            gl_lds(&x_hi[((row0 + (w + 4) * 16) << 8) + kcol + gcoff], &ah[(w + 4) * 512]);
            gl_lds(&x_lo[((row0 + w * 16) << 8) + kcol + gcoff],       &al[w * 512]);
            gl_lds(&x_lo[((row0 + (w + 4) * 16) << 8) + kcol + gcoff], &al[(w + 4) * 512]);
            // b: wave w stages segments {w, w+4, w+8, w+12} of 16
            #pragma unroll
            for (int i = 0; i < 4; ++i) {
                const int seg = w + 4 * i;
                gl_lds(&e_hi[((brow + seg * 16) << 8) + kcol + gcoff], &bh[seg * 512]);
                gl_lds(&e_lo[((brow + seg * 16) << 8) + kcol + gcoff], &bl[seg * 512]);
            }
            __syncthreads();   // compiler drains vmcnt before barrier

            short8 afh[4], afl[4];
            #pragma unroll
            for (int rt = 0; rt < 4; ++rt)
                afh[rt] = *(const short8*)&ah[aoff0 + (rt << 9)];
            #pragma unroll
            for (int rt = 0; rt < 4; ++rt)
                afl[rt] = *(const short8*)&al[aoff0 + (rt << 9)];

            #pragma unroll
            for (int jt = 0; jt < 8; ++jt) {
                short8 bfh = *(const short8*)&bh[boff0 + (jt << 9)];
                short8 bfl = *(const short8*)&bl[boff0 + (jt << 9)];
                #pragma unroll
                for (int rt = 0; rt < 4; ++rt)
                    acc[rt][jt] = __builtin_amdgcn_mfma_f32_16x16x32_bf16(
                        afh[rt], bfh, acc[rt][jt], 0, 0, 0);
                #pragma unroll
                for (int rt = 0; rt < 4; ++rt)
                    acc[rt][jt] = __builtin_amdgcn_mfma_f32_16x16x32_bf16(
                        afl[rt], bfh, acc[rt][jt], 0, 0, 0);
                #pragma unroll
                for (int rt = 0; rt < 4; ++rt)
                    acc[rt][jt] = __builtin_amdgcn_mfma_f32_16x16x32_bf16(
                        afh[rt], bfl, acc[rt][jt], 0, 0, 0);
            }
        }

        #pragma unroll
        for (int jt = 0; jt < 8; ++jt) {
            int c = ct * 256 + wx * 128 + jt * 16 + l15;
            float eec = ee[c];
            #pragma unroll
            for (int rt = 0; rt < 4; ++rt) {
                #pragma unroll
                for (int reg = 0; reg < 4; ++reg) {
                    float s = eec - 2.0f * acc[rt][jt][reg];
                    int slot = rt * 4 + reg;
                    if (s < bestv[slot]) {
                        best2v[slot] = bestv[slot];
                        bestv[slot] = s; besti[slot] = c;
                    } else {
                        best2v[slot] = fminf(best2v[slot], s);
                    }
                }
            }
        }
    }

    #pragma unroll
    for (int slot = 0; slot < 16; ++slot) {
        float bv = bestv[slot]; int bi = besti[slot]; float b2 = best2v[slot];
        #pragma unroll
        for (int off = 8; off >= 1; off >>= 1) {
            float ov  = __shfl_xor(bv, off, 16);
            int   oi  = __shfl_xor(bi, off, 16);
            float ov2 = __shfl_xor(b2, off, 16);
            float nm2 = fminf(fminf(b2, ov2), fmaxf(bv, ov));
            if (ov < bv) { bv = ov; bi = oi; }
            b2 = nm2;
        }
        bestv[slot] = bv; besti[slot] = bi; best2v[slot] = b2;
    }

    if (l15 == 0) {
        #pragma unroll
        for (int rt = 0; rt < 4; ++rt)
            #pragma unroll
            for (int reg = 0; reg < 4; ++reg) {
                int rloc2 = wy * 64 + rt * 16 + quad * 4 + reg;
                int slot = rt * 4 + reg;
                redv[wx][rloc2] = bestv[slot];
                red2[wx][rloc2] = best2v[slot];
                redi[wx][rloc2] = besti[slot];
            }
    }
    __syncthreads();
    if (tid < 128) {
        float v0 = redv[0][tid], v1 = redv[1][tid];
        float s0 = red2[0][tid], s1 = red2[1][tid];
        float m1, m2; int mi;
        if (v0 <= v1) { m1 = v0; mi = redi[0][tid]; m2 = fminf(fminf(s0, s1), v1); }
        else          { m1 = v1; mi = redi[1][tid]; m2 = fminf(fminf(s0, s1), v0); }
        long rowAbs = row0 + tid;
        ind_out[rowAbs] = (float)mi;
        if (m2 - m1 <= WINDOW) {
            int q = atomicAdd(qbase, 1);
            qbase[1 + q] = (int)rowAbs;
        }
    }
}

// ============================================================
// Kernel D (pass 2): exact fp32 rescan of ambiguous rows (8-row batches).
// ============================================================
constexpr int RB = 8;
__global__ __launch_bounds__(256) void pass2_kernel(
    const float* __restrict__ x, const float* __restrict__ embed,
    const float* __restrict__ ee, const int* __restrict__ qbase,
    float* __restrict__ ind_out)
{
    __shared__ float xs[RB][256];
    __shared__ float sv[RB][256];
    __shared__ int   si[RB][256];
    const int tid = threadIdx.x;
    const int count = qbase[0];

    for (int q0 = blockIdx.x * RB; q0 < count; q0 += gridDim.x * RB) {
        const int nr = (count - q0 < RB) ? (count - q0) : RB;
        __syncthreads();
        for (int r = 0; r < nr; ++r)
            xs[r][tid] = x[(long)qbase[1 + q0 + r] * Dd + tid];
        __syncthreads();

        float bv[RB]; int bi[RB];
        #pragma unroll
        for (int r = 0; r < RB; ++r) { bv[r] = FLT_MAX; bi[r] = 0; }

        for (int i = 0; i < Kk / 256; ++i) {
            const int c = i * 256 + tid;
            const float4* er = (const float4*)&embed[(long)c * Dd];
            float dot[RB];
            #pragma unroll
            for (int r = 0; r < RB; ++r) dot[r] = 0.0f;
            for (int d = 0; d < Dd / 4; ++d) {
                float4 e4 = er[d];
                #pragma unroll
                for (int r = 0; r < RB; ++r) {
                    float4 x4 = *(const float4*)&xs[r][d * 4];
                    dot[r] += e4.x * x4.x + e4.y * x4.y + e4.z * x4.z + e4.w * x4.w;
                }
            }
            float eec = ee[c];
            #pragma unroll
            for (int r = 0; r < RB; ++r) {
                float s = eec - 2.0f * dot[r];
                if (s < bv[r]) { bv[r] = s; bi[r] = c; }
            }
        }

        #pragma unroll
        for (int r = 0; r < RB; ++r) { sv[r][tid] = bv[r]; si[r][tid] = bi[r]; }
        __syncthreads();
        for (int off = 128; off >= 1; off >>= 1) {
            if (tid < off) {
                #pragma unroll
                for (int r = 0; r < RB; ++r) {
                    float v2 = sv[r][tid + off]; int i2 = si[r][tid + off];
                    if (v2 < sv[r][tid] || (v2 == sv[r][tid] && i2 < si[r][tid])) {
                        sv[r][tid] = v2; si[r][tid] = i2;
                    }
                }
            }
            __syncthreads();
        }
        if (tid < nr)
            ind_out[qbase[1 + q0 + tid]] = (float)si[tid][0];
        __syncthreads();
    }
}

// ============================================================
// Kernel E: quantize gather (pure BW, no atomics). One wave per row.
// ============================================================
__global__ __launch_bounds__(256) void quant_gather_kernel(
    const float* __restrict__ embed, const float* __restrict__ ind_f,
    float* __restrict__ quant)
{
    long row  = (long)blockIdx.x * 4 + (threadIdx.x >> 6);
    int  lane = threadIdx.x & 63;
    int  idx  = (int)ind_f[row];
    float4 ev = *(const float4*)&embed[(long)idx * Dd + lane * 4];
    *(float4*)&quant[row * Dd + lane * 4] = ev;
}

// ============================================================
// Kernel F: pull-based segmented sum, v2: CODES=8 codes per block.
// One strip scan matches 8 codes (uniform switch keeps acc statically
// indexed -> registers, rule #20). ind traffic /8 vs v1; identical
// per-accumulator add order -> bitwise identical partials.
// ============================================================
template <int USE_ATOMIC>
__global__ __launch_bounds__(256) void segsum_kernel(
    const float* __restrict__ x, const float* __restrict__ ind_f,
    float* __restrict__ dst, float* __restrict__ counts)
{
    __shared__ float part[CODES][4][256];   // 32KB
    __shared__ float cnt_l[CODES][4];
    const int tid  = threadIdx.x;
    const int w    = tid >> 6;
    const int lane = tid & 63;
    const int k0   = (blockIdx.x >> 3) * CODES;
    const int s    = blockIdx.x & 7;

    constexpr int STRIP = Nn / PARTS;          // 8192 rows
    constexpr int WAVE_ROWS = STRIP / 4;       // 2048 rows per wave
    const int base0 = s * STRIP + w * WAVE_ROWS;

    float4 acc[CODES];
    int    cnt[CODES];
    #pragma unroll
    for (int c = 0; c < CODES; ++c) { acc[c] = (float4){0.f,0.f,0.f,0.f}; cnt[c] = 0; }

    for (int win = 0; win < WAVE_ROWS; win += 64) {
        int idx = (int)ind_f[base0 + win + lane];
        unsigned rel = (unsigned)(idx - k0);
        unsigned long long m = __ballot(rel < (unsigned)CODES);
        while (m) {
            int l = __ffsll((unsigned long long)m) - 1;
            m &= m - 1;
            int code = __shfl((int)rel, l, 64);   // wave-uniform
            long row = base0 + win + l;
            float4 v = *(const float4*)&x[row * Dd + lane * 4];
            switch (code) {
                case 0: acc[0].x+=v.x; acc[0].y+=v.y; acc[0].z+=v.z; acc[0].w+=v.w; cnt[0]++; break;
                case 1: acc[1].x+=v.x; acc[1].y+=v.y; acc[1].z+=v.z; acc[1].w+=v.w; cnt[1]++; break;
                case 2: acc[2].x+=v.x; acc[2].y+=v.y; acc[2].z+=v.z; acc[2].w+=v.w; cnt[2]++; break;
                case 3: acc[3].x+=v.x; acc[3].y+=v.y; acc[3].z+=v.z; acc[3].w+=v.w; cnt[3]++; break;
                case 4: acc[4].x+=v.x; acc[4].y+=v.y; acc[4].z+=v.z; acc[4].w+=v.w; cnt[4]++; break;
                case 5: acc[5].x+=v.x; acc[5].y+=v.y; acc[5].z+=v.z; acc[5].w+=v.w; cnt[5]++; break;
                case 6: acc[6].x+=v.x; acc[6].y+=v.y; acc[6].z+=v.z; acc[6].w+=v.w; cnt[6]++; break;
                case 7: acc[7].x+=v.x; acc[7].y+=v.y; acc[7].z+=v.z; acc[7].w+=v.w; cnt[7]++; break;
            }
        }
    }

    #pragma unroll
    for (int c = 0; c < CODES; ++c) {
        *(float4*)&part[c][w][lane * 4] = acc[c];
        if (lane == 0) cnt_l[c][w] = (float)cnt[c];
    }
    __syncthreads();

    #pragma unroll
    for (int c = 0; c < CODES; ++c) {
        float sum = part[c][0][tid] + part[c][1][tid] + part[c][2][tid] + part[c][3][tid];
        if (USE_ATOMIC) {
            if (sum != 0.0f) atomicAdd(&dst[(long)(k0 + c) * Dd + tid], sum);
        } else {
            dst[((long)s * Kk + (k0 + c)) * Dd + tid] = sum;
        }
    }
    if (tid < CODES)
        atomicAdd(&counts[k0 + tid],
                  cnt_l[tid][0] + cnt_l[tid][1] + cnt_l[tid][2] + cnt_l[tid][3]);
}

// ============================================================
// Kernel G: new_cluster_size + total (single block)
// ============================================================
__global__ __launch_bounds__(256) void ema_cs_kernel(
    const float* __restrict__ cs, const float* __restrict__ counts,
    float* __restrict__ ncs, float* __restrict__ total_ws)
{
    __shared__ float red[256];
    int tid = threadIdx.x;
    float s = 0.0f;
    #pragma unroll
    for (int i = 0; i < 8; ++i) {
        int k = tid + i * 256;
        float v = cs[k] * DECAY + OMD * counts[k];
        ncs[k] = v;
        s += v;
    }
    red[tid] = s;
    __syncthreads();
    #pragma unroll
    for (int off = 128; off >= 1; off >>= 1) {
        if (tid < off) red[tid] += red[tid + off];
        __syncthreads();
    }
    if (tid == 0) total_ws[0] = red[0];
}

// ============================================================
// Kernel H: combine partials -> embed_sum; nea; ne.
// ============================================================
__global__ __launch_bounds__(256) void nea_ne_kernel(
    const float* __restrict__ ea, const float* __restrict__ partials,
    int nparts, const float* __restrict__ ncs, const float* __restrict__ total_ws,
    float* __restrict__ nea, float* __restrict__ ne)
{
    long g = ((long)blockIdx.x * 256 + threadIdx.x) * 4;
    int  k = (int)(g >> 8);
    int  d = (int)(g & 255);

    float4 sv = {0.f, 0.f, 0.f, 0.f};
    for (int p = 0; p < nparts; ++p) {
        float4 pv = *(const float4*)&partials[((long)p * Kk + k) * Dd + d];
        sv.x += pv.x; sv.y += pv.y; sv.z += pv.z; sv.w += pv.w;
    }

    float4 av = *(const float4*)&ea[g];
    float4 out_nea;
    out_nea.x = av.x * DECAY + OMD * sv.x;
    out_nea.y = av.y * DECAY + OMD * sv.y;
    out_nea.z = av.z * DECAY + OMD * sv.z;
    out_nea.w = av.w * DECAY + OMD * sv.w;
    *(float4*)&nea[g] = out_nea;

    float total = total_ws[0];
    float sm = (ncs[k] + EPSF) / (total + EPSF * (float)Kk) * total;
    float inv = 1.0f / sm;
    float4 out_ne;
    out_ne.x = out_nea.x * inv;
    out_ne.y = out_nea.y * inv;
    out_ne.z = out_nea.z * inv;
    out_ne.w = out_nea.w * inv;
    *(float4*)&ne[g] = out_ne;
}

// ============================================================
extern "C" void kernel_launch(void* const* d_in, const int* in_sizes, int n_in,
                              void* d_out, int out_size, void* d_ws, size_t ws_size,
                              hipStream_t stream)
{
    const float* x     = (const float*)d_in[0];
    const float* embed = (const float*)d_in[1];
    const float* cs    = (const float*)d_in[2];
    const float* ea    = (const float*)d_in[3];

    float* out   = (float*)d_out;
    float* quant = out + OUT_QUANT;
    float* ind_f = out + OUT_IND;
    float* ncs   = out + OUT_NCS;
    float* nea   = out + OUT_NEA;
    float* ne    = out + OUT_NE;

    float* ws     = (float*)d_ws;
    float* counts = ws + WS_COUNTS;
    float* total  = ws + WS_TOTAL;
    float* ee     = ws + WS_EE;
    float* big    = ws + WS_BIG;     // embed_sum (atomic) or partials (ws path)

    // scratch inside d_out
    ushort* x_hi = (ushort*)(out + OUT_QUANT);
    ushort* x_lo = (ushort*)(out + OUT_QUANT + Nn * (Dd / 2));
    ushort* e_hi = (ushort*)(out + OUT_NEA);
    ushort* e_lo = (ushort*)(out + OUT_NEA + Kk * (Dd / 2));
    int*    qb   = (int*)(out + OUT_NE);

    const size_t need_partials =
        (size_t)(WS_BIG + (long)PARTS * Kk * Dd) * sizeof(float) + 1024;
    const bool use_ws_partials = ws_size >= need_partials;

    hipMemsetAsync(counts, 0, Kk * sizeof(float), stream);
    hipMemsetAsync(qb, 0, sizeof(int), stream);
    if (!use_ws_partials)
        hipMemsetAsync(big, 0, (size_t)Kk * Dd * sizeof(float), stream);

    convert_x_kernel<<<(Nn * Dd / 4) / 256, 256, 0, stream>>>(x, x_hi, x_lo);
    convert_e_kernel<<<Kk / 4, 256, 0, stream>>>(embed, e_hi, e_lo, ee);
    pass1_kernel<<<Nn / 128, 256, 0, stream>>>(x_hi, x_lo, e_hi, e_lo, ee, ind_f, qb);
    pass2_kernel<<<256, 256, 0, stream>>>(x, embed, ee, qb, ind_f);
    quant_gather_kernel<<<Nn / 4, 256, 0, stream>>>(embed, ind_f, quant);
    if (use_ws_partials)
        segsum_kernel<0><<<(Kk / CODES) * PARTS, 256, 0, stream>>>(x, ind_f, big, counts);
    else
        segsum_kernel<1><<<(Kk / CODES) * PARTS, 256, 0, stream>>>(x, ind_f, big, counts);
    ema_cs_kernel<<<1, 256, 0, stream>>>(cs, counts, ncs, total);
    nea_ne_kernel<<<(Kk * Dd / 4) / 256, 256, 0, stream>>>(
        ea, big, use_ws_partials ? PARTS : 1, ncs, total, nea, ne);
}

// Round 4
// 478.868 us; speedup vs baseline: 1.4230x; 1.0181x over previous
//
#include <hip/hip_runtime.h>
#include <hip/hip_fp16.h>
#include <float.h>

#define DECAY 0.99f
#define OMD   0.01f
#define EPSF  1e-6f

constexpr int Bb = 8, Ss = 8192, Dd = 256, Kk = 2048;
constexpr int Nn = Bb * Ss;                 // 65536 rows

// ---- output layout (floats) ----
constexpr long OUT_QUANT = 0;                         // 16777216 floats
constexpr long OUT_IND   = (long)Nn * Dd;             // 16777216
constexpr long OUT_NCS   = OUT_IND + Nn;              // 16842752
constexpr long OUT_NEA   = OUT_NCS + Kk;              // 16844800
constexpr long OUT_NE    = OUT_NEA + (long)Kk * Dd;   // 17369088

// ---- workspace layout (floats) ----
constexpr long WS_COUNTS = 0;                         // K
constexpr long WS_TOTAL  = 2048;                      // 1
constexpr long WS_EE     = 2112;                      // K
constexpr long WS_BIG    = 4160;                      // embed_sum (atomic path)
                                                      // or 8 partials (ws path)
constexpr int  PARTS     = 8;                         // strip split for segsum
constexpr int  CODES     = 8;                         // codes per segsum block

typedef __attribute__((ext_vector_type(8))) short short8;
typedef __attribute__((ext_vector_type(8))) _Float16 half8;
typedef __attribute__((ext_vector_type(4))) float floatx4;

// fp16 single-pass certainty window (round-4): per-dist error std ~0.018,
// realistic max over all rows ~0.13; rows whose approx top-2 gap <= WINDOW
// get an exact fp32 rescan in pass 2. 0.5 = ~20 sigma margin.
#define WINDOW 0.5f

// async global->LDS, 16B per lane, LDS dest = wave-uniform base + lane*16
__device__ __forceinline__ void gl_lds(const ushort* g, ushort* l)
{
    __builtin_amdgcn_global_load_lds(
        (const __attribute__((address_space(1))) void*)g,
        (__attribute__((address_space(3))) void*)l,
        16, 0, 0);
}

__device__ __forceinline__ ushort f2h(float v)
{
    __half h = __float2half(v);
    return *(ushort*)&h;
}

// ============================================================
// Kernel A: x -> x_h (fp16). 8 floats per thread.
// ============================================================
__global__ __launch_bounds__(256) void convert_x_kernel(
    const float* __restrict__ x, ushort* __restrict__ x_h)
{
    long base = ((long)blockIdx.x * 256 + threadIdx.x) * 8;
    float4 a = *(const float4*)&x[base];
    float4 b = *(const float4*)&x[base + 4];
    short8 h;
    h[0] = (short)f2h(a.x); h[1] = (short)f2h(a.y);
    h[2] = (short)f2h(a.z); h[3] = (short)f2h(a.w);
    h[4] = (short)f2h(b.x); h[5] = (short)f2h(b.y);
    h[6] = (short)f2h(b.z); h[7] = (short)f2h(b.w);
    *(short8*)&x_h[base] = h;
}

// ============================================================
// Kernel B: embed -> e_h (fp16) and ee[k] = sum_d embed[k][d]^2 (fp32 exact)
// ============================================================
__global__ __launch_bounds__(256) void convert_e_kernel(
    const float* __restrict__ embed, ushort* __restrict__ e_h,
    float* __restrict__ ee)
{
    int row  = blockIdx.x * 4 + (threadIdx.x >> 6);
    int lane = threadIdx.x & 63;
    long base = (long)row * Dd + lane * 4;
    float4 v = *(const float4*)&embed[base];
    float s = v.x * v.x + v.y * v.y + v.z * v.z + v.w * v.w;
    ushort4 h;
    h.x = f2h(v.x); h.y = f2h(v.y); h.z = f2h(v.z); h.w = f2h(v.w);
    *(ushort4*)&e_h[base] = h;
    #pragma unroll
    for (int off = 32; off >= 1; off >>= 1)
        s += __shfl_xor(s, off, 64);
    if (lane == 0) ee[row] = s;
}

// ============================================================
// Kernel C (pass 1): fp16 single-pass MFMA GEMM + top-2 argmin.
//
// v5 (round 4): split-bf16 3-pass -> fp16 1-pass (3x fewer MFMAs, 2x less
// LDS + staging traffic); exactness preserved by WINDOW=0.5 + pass2 rescan.
// Phase K-width 64 (was 32): half the barrier/drain events. LDS 51KB,
// 2 blocks/CU (acc=128 AGPR caps occupancy; unchanged from v4).
//
// Swizzle (K=64, 8 chunks of 16B per row): LDS slot s of row r holds global
// chunk s ^ (r&7). Staging unit = 8 rows x 64 cols = 1KB per gl_lds; source
// pre-swizzled per-lane (rloc=lane>>3, chunk=(lane&7)^rloc); read applies
// slot = cc ^ (r&7). Balanced: 32B/bank per wave read instr.
// ============================================================
__global__ __attribute__((amdgpu_waves_per_eu(2, 2))) __launch_bounds__(256)
void pass1_kernel(
    const ushort* __restrict__ x_h, const ushort* __restrict__ e_h,
    const float* __restrict__ ee, float* __restrict__ ind_out,
    int* __restrict__ qbase)
{
    __shared__ __attribute__((aligned(16))) ushort ah[128 * 64];   // 16KB
    __shared__ __attribute__((aligned(16))) ushort bh[256 * 64];   // 32KB
    __shared__ float  redv[2][128];
    __shared__ float  red2[2][128];
    __shared__ int    redi[2][128];

    const int tid  = threadIdx.x;
    const int lane = tid & 63;
    const int quad = lane >> 4;
    const int l15  = lane & 15;
    const int w    = tid >> 6;
    const int wy   = w >> 1;
    const int wx   = w & 1;
    const long row0 = (long)blockIdx.x * 128;

    // staging source pre-swizzle: unit = 8 rows; lane covers
    // (rloc = lane>>3, slot = lane&7); slot s holds chunk s ^ rloc.
    const int rloc   = lane >> 3;
    const int cchunk = (lane & 7) ^ rloc;
    const int gcoff  = rloc * 256 + cchunk * 8;   // ushorts from (unit row0, kcol)

    // fragment read swizzle: row = ...+l15 -> r&7 = l15&7
    const int s7 = l15 & 7;

    float bestv[16], best2v[16];
    int   besti[16];
    #pragma unroll
    for (int i = 0; i < 16; ++i) { bestv[i] = FLT_MAX; best2v[i] = FLT_MAX; besti[i] = 0; }

    for (int ct = 0; ct < Kk / 256; ++ct) {
        floatx4 acc[4][8];
        #pragma unroll
        for (int rt = 0; rt < 4; ++rt)
            #pragma unroll
            for (int jt = 0; jt < 8; ++jt)
                acc[rt][jt] = (floatx4){0.f, 0.f, 0.f, 0.f};

        const long brow = (long)ct * 256;

        for (int kc = 0; kc < 4; ++kc) {
            const int kcol = kc * 64;

            __syncthreads();   // prior phase's fragment reads done
            // a: 16 units of 8 rows; wave w stages u = w + 4i, i=0..3
            #pragma unroll
            for (int i = 0; i < 4; ++i) {
                const int u = w + 4 * i;
                gl_lds(&x_h[((row0 + u * 8) << 8) + kcol + gcoff], &ah[u * 512]);
            }
            // b: 32 units; wave w stages u = w + 4i, i=0..7
            #pragma unroll
            for (int i = 0; i < 8; ++i) {
                const int u = w + 4 * i;
                gl_lds(&e_h[((brow + u * 8) << 8) + kcol + gcoff], &bh[u * 512]);
            }
            __syncthreads();   // compiler drains vmcnt before barrier

            #pragma unroll
            for (int ks = 0; ks < 2; ++ks) {
                const int cterm = (((ks * 4 + quad) ^ s7) * 8);
                half8 af[4];
                #pragma unroll
                for (int rt = 0; rt < 4; ++rt)
                    af[rt] = *(const half8*)&ah[((wy * 64 + rt * 16 + l15) << 6) + cterm];
                #pragma unroll
                for (int jt = 0; jt < 8; ++jt) {
                    half8 bf = *(const half8*)&bh[((wx * 128 + jt * 16 + l15) << 6) + cterm];
                    #pragma unroll
                    for (int rt = 0; rt < 4; ++rt)
                        acc[rt][jt] = __builtin_amdgcn_mfma_f32_16x16x32_f16(
                            af[rt], bf, acc[rt][jt], 0, 0, 0);
                }
            }
        }

        #pragma unroll
        for (int jt = 0; jt < 8; ++jt) {
            int c = ct * 256 + wx * 128 + jt * 16 + l15;
            float eec = ee[c];
            #pragma unroll
            for (int rt = 0; rt < 4; ++rt) {
                #pragma unroll
                for (int reg = 0; reg < 4; ++reg) {
                    float s = eec - 2.0f * acc[rt][jt][reg];
                    int slot = rt * 4 + reg;
                    if (s < bestv[slot]) {
                        best2v[slot] = bestv[slot];
                        bestv[slot] = s; besti[slot] = c;
                    } else {
                        best2v[slot] = fminf(best2v[slot], s);
                    }
                }
            }
        }
    }

    #pragma unroll
    for (int slot = 0; slot < 16; ++slot) {
        float bv = bestv[slot]; int bi = besti[slot]; float b2 = best2v[slot];
        #pragma unroll
        for (int off = 8; off >= 1; off >>= 1) {
            float ov  = __shfl_xor(bv, off, 16);
            int   oi  = __shfl_xor(bi, off, 16);
            float ov2 = __shfl_xor(b2, off, 16);
            float nm2 = fminf(fminf(b2, ov2), fmaxf(bv, ov));
            if (ov < bv) { bv = ov; bi = oi; }
            b2 = nm2;
        }
        bestv[slot] = bv; besti[slot] = bi; best2v[slot] = b2;
    }

    if (l15 == 0) {
        #pragma unroll
        for (int rt = 0; rt < 4; ++rt)
            #pragma unroll
            for (int reg = 0; reg < 4; ++reg) {
                int rloc2 = wy * 64 + rt * 16 + quad * 4 + reg;
                int slot = rt * 4 + reg;
                redv[wx][rloc2] = bestv[slot];
                red2[wx][rloc2] = best2v[slot];
                redi[wx][rloc2] = besti[slot];
            }
    }
    __syncthreads();
    if (tid < 128) {
        float v0 = redv[0][tid], v1 = redv[1][tid];
        float s0 = red2[0][tid], s1 = red2[1][tid];
        float m1, m2; int mi;
        if (v0 <= v1) { m1 = v0; mi = redi[0][tid]; m2 = fminf(fminf(s0, s1), v1); }
        else          { m1 = v1; mi = redi[1][tid]; m2 = fminf(fminf(s0, s1), v0); }
        long rowAbs = row0 + tid;
        ind_out[rowAbs] = (float)mi;
        if (m2 - m1 <= WINDOW) {
            int q = atomicAdd(qbase, 1);
            qbase[1 + q] = (int)rowAbs;
        }
    }
}

// ============================================================
// Kernel D (pass 2): exact fp32 rescan of ambiguous rows (8-row batches).
// ============================================================
constexpr int RB = 8;
__global__ __launch_bounds__(256) void pass2_kernel(
    const float* __restrict__ x, const float* __restrict__ embed,
    const float* __restrict__ ee, const int* __restrict__ qbase,
    float* __restrict__ ind_out)
{
    __shared__ float xs[RB][256];
    __shared__ float sv[RB][256];
    __shared__ int   si[RB][256];
    const int tid = threadIdx.x;
    const int count = qbase[0];

    for (int q0 = blockIdx.x * RB; q0 < count; q0 += gridDim.x * RB) {
        const int nr = (count - q0 < RB) ? (count - q0) : RB;
        __syncthreads();
        for (int r = 0; r < nr; ++r)
            xs[r][tid] = x[(long)qbase[1 + q0 + r] * Dd + tid];
        __syncthreads();

        float bv[RB]; int bi[RB];
        #pragma unroll
        for (int r = 0; r < RB; ++r) { bv[r] = FLT_MAX; bi[r] = 0; }

        for (int i = 0; i < Kk / 256; ++i) {
            const int c = i * 256 + tid;
            const float4* er = (const float4*)&embed[(long)c * Dd];
            float dot[RB];
            #pragma unroll
            for (int r = 0; r < RB; ++r) dot[r] = 0.0f;
            for (int d = 0; d < Dd / 4; ++d) {
                float4 e4 = er[d];
                #pragma unroll
                for (int r = 0; r < RB; ++r) {
                    float4 x4 = *(const float4*)&xs[r][d * 4];
                    dot[r] += e4.x * x4.x + e4.y * x4.y + e4.z * x4.z + e4.w * x4.w;
                }
            }
            float eec = ee[c];
            #pragma unroll
            for (int r = 0; r < RB; ++r) {
                float s = eec - 2.0f * dot[r];
                if (s < bv[r]) { bv[r] = s; bi[r] = c; }
            }
        }

        #pragma unroll
        for (int r = 0; r < RB; ++r) { sv[r][tid] = bv[r]; si[r][tid] = bi[r]; }
        __syncthreads();
        for (int off = 128; off >= 1; off >>= 1) {
            if (tid < off) {
                #pragma unroll
                for (int r = 0; r < RB; ++r) {
                    float v2 = sv[r][tid + off]; int i2 = si[r][tid + off];
                    if (v2 < sv[r][tid] || (v2 == sv[r][tid] && i2 < si[r][tid])) {
                        sv[r][tid] = v2; si[r][tid] = i2;
                    }
                }
            }
            __syncthreads();
        }
        if (tid < nr)
            ind_out[qbase[1 + q0 + tid]] = (float)si[tid][0];
        __syncthreads();
    }
}

// ============================================================
// Kernel E: quantize gather (pure BW, no atomics). One wave per row.
// ============================================================
__global__ __launch_bounds__(256) void quant_gather_kernel(
    const float* __restrict__ embed, const float* __restrict__ ind_f,
    float* __restrict__ quant)
{
    long row  = (long)blockIdx.x * 4 + (threadIdx.x >> 6);
    int  lane = threadIdx.x & 63;
    int  idx  = (int)ind_f[row];
    float4 ev = *(const float4*)&embed[(long)idx * Dd + lane * 4];
    *(float4*)&quant[row * Dd + lane * 4] = ev;
}

// ============================================================
// Kernel F: pull-based segmented sum, CODES=8 codes per block.
// ============================================================
template <int USE_ATOMIC>
__global__ __launch_bounds__(256) void segsum_kernel(
    const float* __restrict__ x, const float* __restrict__ ind_f,
    float* __restrict__ dst, float* __restrict__ counts)
{
    __shared__ float part[CODES][4][256];   // 32KB
    __shared__ float cnt_l[CODES][4];
    const int tid  = threadIdx.x;
    const int w    = tid >> 6;
    const int lane = tid & 63;
    const int k0   = (blockIdx.x >> 3) * CODES;
    const int s    = blockIdx.x & 7;

    constexpr int STRIP = Nn / PARTS;          // 8192 rows
    constexpr int WAVE_ROWS = STRIP / 4;       // 2048 rows per wave
    const int base0 = s * STRIP + w * WAVE_ROWS;

    float4 acc[CODES];
    int    cnt[CODES];
    #pragma unroll
    for (int c = 0; c < CODES; ++c) { acc[c] = (float4){0.f,0.f,0.f,0.f}; cnt[c] = 0; }

    for (int win = 0; win < WAVE_ROWS; win += 64) {
        int idx = (int)ind_f[base0 + win + lane];
        unsigned rel = (unsigned)(idx - k0);
        unsigned long long m = __ballot(rel < (unsigned)CODES);
        while (m) {
            int l = __ffsll((unsigned long long)m) - 1;
            m &= m - 1;
            int code = __shfl((int)rel, l, 64);   // wave-uniform
            long row = base0 + win + l;
            float4 v = *(const float4*)&x[row * Dd + lane * 4];
            switch (code) {
                case 0: acc[0].x+=v.x; acc[0].y+=v.y; acc[0].z+=v.z; acc[0].w+=v.w; cnt[0]++; break;
                case 1: acc[1].x+=v.x; acc[1].y+=v.y; acc[1].z+=v.z; acc[1].w+=v.w; cnt[1]++; break;
                case 2: acc[2].x+=v.x; acc[2].y+=v.y; acc[2].z+=v.z; acc[2].w+=v.w; cnt[2]++; break;
                case 3: acc[3].x+=v.x; acc[3].y+=v.y; acc[3].z+=v.z; acc[3].w+=v.w; cnt[3]++; break;
                case 4: acc[4].x+=v.x; acc[4].y+=v.y; acc[4].z+=v.z; acc[4].w+=v.w; cnt[4]++; break;
                case 5: acc[5].x+=v.x; acc[5].y+=v.y; acc[5].z+=v.z; acc[5].w+=v.w; cnt[5]++; break;
                case 6: acc[6].x+=v.x; acc[6].y+=v.y; acc[6].z+=v.z; acc[6].w+=v.w; cnt[6]++; break;
                case 7: acc[7].x+=v.x; acc[7].y+=v.y; acc[7].z+=v.z; acc[7].w+=v.w; cnt[7]++; break;
            }
        }
    }

    #pragma unroll
    for (int c = 0; c < CODES; ++c) {
        *(float4*)&part[c][w][lane * 4] = acc[c];
        if (lane == 0) cnt_l[c][w] = (float)cnt[c];
    }
    __syncthreads();

    #pragma unroll
    for (int c = 0; c < CODES; ++c) {
        float sum = part[c][0][tid] + part[c][1][tid] + part[c][2][tid] + part[c][3][tid];
        if (USE_ATOMIC) {
            if (sum != 0.0f) atomicAdd(&dst[(long)(k0 + c) * Dd + tid], sum);
        } else {
            dst[((long)s * Kk + (k0 + c)) * Dd + tid] = sum;
        }
    }
    if (tid < CODES)
        atomicAdd(&counts[k0 + tid],
                  cnt_l[tid][0] + cnt_l[tid][1] + cnt_l[tid][2] + cnt_l[tid][3]);
}

// ============================================================
// Kernel G: new_cluster_size + total (single block)
// ============================================================
__global__ __launch_bounds__(256) void ema_cs_kernel(
    const float* __restrict__ cs, const float* __restrict__ counts,
    float* __restrict__ ncs, float* __restrict__ total_ws)
{
    __shared__ float red[256];
    int tid = threadIdx.x;
    float s = 0.0f;
    #pragma unroll
    for (int i = 0; i < 8; ++i) {
        int k = tid + i * 256;
        float v = cs[k] * DECAY + OMD * counts[k];
        ncs[k] = v;
        s += v;
    }
    red[tid] = s;
    __syncthreads();
    #pragma unroll
    for (int off = 128; off >= 1; off >>= 1) {
        if (tid < off) red[tid] += red[tid + off];
        __syncthreads();
    }
    if (tid == 0) total_ws[0] = red[0];
}

// ============================================================
// Kernel H: combine partials -> embed_sum; nea; ne.
// ============================================================
__global__ __launch_bounds__(256) void nea_ne_kernel(
    const float* __restrict__ ea, const float* __restrict__ partials,
    int nparts, const float* __restrict__ ncs, const float* __restrict__ total_ws,
    float* __restrict__ nea, float* __restrict__ ne)
{
    long g = ((long)blockIdx.x * 256 + threadIdx.x) * 4;
    int  k = (int)(g >> 8);
    int  d = (int)(g & 255);

    float4 sv = {0.f, 0.f, 0.f, 0.f};
    for (int p = 0; p < nparts; ++p) {
        float4 pv = *(const float4*)&partials[((long)p * Kk + k) * Dd + d];
        sv.x += pv.x; sv.y += pv.y; sv.z += pv.z; sv.w += pv.w;
    }

    float4 av = *(const float4*)&ea[g];
    float4 out_nea;
    out_nea.x = av.x * DECAY + OMD * sv.x;
    out_nea.y = av.y * DECAY + OMD * sv.y;
    out_nea.z = av.z * DECAY + OMD * sv.z;
    out_nea.w = av.w * DECAY + OMD * sv.w;
    *(float4*)&nea[g] = out_nea;

    float total = total_ws[0];
    float sm = (ncs[k] + EPSF) / (total + EPSF * (float)Kk) * total;
    float inv = 1.0f / sm;
    float4 out_ne;
    out_ne.x = out_nea.x * inv;
    out_ne.y = out_nea.y * inv;
    out_ne.z = out_nea.z * inv;
    out_ne.w = out_nea.w * inv;
    *(float4*)&ne[g] = out_ne;
}

// ============================================================
extern "C" void kernel_launch(void* const* d_in, const int* in_sizes, int n_in,
                              void* d_out, int out_size, void* d_ws, size_t ws_size,
                              hipStream_t stream)
{
    const float* x     = (const float*)d_in[0];
    const float* embed = (const float*)d_in[1];
    const float* cs    = (const float*)d_in[2];
    const float* ea    = (const float*)d_in[3];

    float* out   = (float*)d_out;
    float* quant = out + OUT_QUANT;
    float* ind_f = out + OUT_IND;
    float* ncs   = out + OUT_NCS;
    float* nea   = out + OUT_NEA;
    float* ne    = out + OUT_NE;

    float* ws     = (float*)d_ws;
    float* counts = ws + WS_COUNTS;
    float* total  = ws + WS_TOTAL;
    float* ee     = ws + WS_EE;
    float* big    = ws + WS_BIG;     // embed_sum (atomic) or partials (ws path)

    // scratch inside d_out
    ushort* x_h = (ushort*)(out + OUT_QUANT);   // 32MB fp16, quant region
    ushort* e_h = (ushort*)(out + OUT_NEA);     // 1MB fp16, nea region
    int*    qb  = (int*)(out + OUT_NE);

    const size_t need_partials =
        (size_t)(WS_BIG + (long)PARTS * Kk * Dd) * sizeof(float) + 1024;
    const bool use_ws_partials = ws_size >= need_partials;

    hipMemsetAsync(counts, 0, Kk * sizeof(float), stream);
    hipMemsetAsync(qb, 0, sizeof(int), stream);
    if (!use_ws_partials)
        hipMemsetAsync(big, 0, (size_t)Kk * Dd * sizeof(float), stream);

    convert_x_kernel<<<(Nn * Dd / 8) / 256, 256, 0, stream>>>(x, x_h);
    convert_e_kernel<<<Kk / 4, 256, 0, stream>>>(embed, e_h, ee);
    pass1_kernel<<<Nn / 128, 256, 0, stream>>>(x_h, e_h, ee, ind_f, qb);
    pass2_kernel<<<512, 256, 0, stream>>>(x, embed, ee, qb, ind_f);
    quant_gather_kernel<<<Nn / 4, 256, 0, stream>>>(embed, ind_f, quant);
    if (use_ws_partials)
        segsum_kernel<0><<<(Kk / CODES) * PARTS, 256, 0, stream>>>(x, ind_f, big, counts);
    else
        segsum_kernel<1><<<(Kk / CODES) * PARTS, 256, 0, stream>>>(x, ind_f, big, counts);
    ema_cs_kernel<<<1, 256, 0, stream>>>(cs, counts, ncs, total);
    nea_ne_kernel<<<(Kk * Dd / 4) / 256, 256, 0, stream>>>(
        ea, big, use_ws_partials ? PARTS : 1, ncs, total, nea, ne);
}